// Round 12
// baseline (13993.752 us; speedup 1.0000x reference)
//
#include <hip/hip_runtime.h>
#include <cstdint>
#include <cstddef>

// ---------------------------------------------------------------------------
// GConvGRU (ChebConv K=3, 2 layers) + readout, for MI355X.
// R12: R11 retry — nontemporal act loads in gateA via clang ext_vector_type
//      (R11 failed to compile: builtin rejects HIP_vector_type*). Theory: act
//      stream evicts the 60KB weight set from 32KB L1 (R6 evidence); nt loads
//      keep weights L1-resident at zero occupancy/LDS cost.
//      Everything else identical to R10 (12.81ms, passing).
// ---------------------------------------------------------------------------

typedef float nt_f4 __attribute__((ext_vector_type(4)));   // native vec for nt loads

__device__ __forceinline__ float sigmoidf_(float x){ return 1.f/(1.f+__expf(-x)); }

// ---------------- preprocessing ----------------

__global__ void detect_kernel(const unsigned* __restrict__ buf, int ndw, int* flag){
  int i = blockIdx.x*blockDim.x + threadIdx.x;
  int j = 2*i + 1;
  if (j < ndw && buf[j] != 0u) atomicOr(flag, 1);   // flag=1 -> int32
}

__global__ void convert_kernel(const void* __restrict__ eidx, const float* __restrict__ w,
                               int E, const int* __restrict__ flag,
                               int* __restrict__ row32, int* __restrict__ col32,
                               float* __restrict__ deg, int* __restrict__ cnt){
  int e = blockIdx.x*blockDim.x + threadIdx.x;
  if (e >= E) return;
  int r, c;
  if (*flag){ const int* p = (const int*)eidx; r = p[e]; c = p[E+e]; }
  else { const long long* p = (const long long*)eidx; r = (int)p[e]; c = (int)p[(size_t)E+e]; }
  row32[e] = r; col32[e] = c;
  atomicAdd(deg + r, w[e]);
  atomicAdd(cnt + c, 1);
}

__global__ void node_prep_kernel(const float* __restrict__ deg, float* __restrict__ dinv,
                                 float* __restrict__ dg, int N){
  int n = blockIdx.x*blockDim.x + threadIdx.x;
  if (n >= N) return;
  float d = deg[n];
  if (d > 0.f){ dinv[n] = rsqrtf(d); dg[n] = 0.f; }
  else        { dinv[n] = 0.f;       dg[n] = -1.f; }
}

// Exclusive scan of PADDED counts ((cnt+7)&~7) -> ptr[N+1]. 1 block, 1024 thr.
__global__ void scan_kernel(const int* __restrict__ cnt, int* __restrict__ ptrout, int N){
  __shared__ int s[1024];
  int t = threadIdx.x;
  int chunk = (N + 1023) / 1024;
  int a0 = t*chunk, a1 = min(N, a0 + chunk);
  int sum = 0;
  for (int i = a0; i < a1; ++i) sum += (cnt[i]+7)&~7;
  s[t] = sum; __syncthreads();
  for (int off = 1; off < 1024; off <<= 1){
    int v = (t >= off) ? s[t-off] : 0;
    __syncthreads();
    s[t] += v;
    __syncthreads();
  }
  int run = (t == 0) ? 0 : s[t-1];
  for (int i = a0; i < a1; ++i){ ptrout[i] = run; run += (cnt[i]+7)&~7; }
  if (t == 1023) ptrout[N] = s[1023];
}

__global__ void fill_kernel(const int* __restrict__ row32, const int* __restrict__ col32,
                            const float* __restrict__ w, const float* __restrict__ dinv,
                            const int* __restrict__ ptrv, int* __restrict__ cnt2,
                            int* __restrict__ srcs, float* __restrict__ vals, int E){
  int e = blockIdx.x*blockDim.x + threadIdx.x;
  if (e >= E) return;
  int r = row32[e], c = col32[e];
  int p = ptrv[c] + atomicAdd(cnt2 + c, 1);
  srcs[p] = r;
  vals[p] = -w[e] * dinv[r] * dinv[c];
}

// Pad slots gather (src=0, val=0): bit-identical arithmetic, L2-hot row.
__global__ void pad_kernel(const int* __restrict__ cnt, const int* __restrict__ ptrv,
                           int* __restrict__ srcs, float* __restrict__ vals, int N){
  int n = blockIdx.x*blockDim.x + threadIdx.x;
  if (n >= N) return;
  int base = ptrv[n];
  int real = cnt[n];
  int padded = ptrv[n+1] - base;
  for (int j = real; j < padded; ++j){ srcs[base+j] = 0; vals[base+j] = 0.f; }
}

// ---------------- SpMM: y = alpha*(A x + diag*x) + beta*z ----------------
__global__ __launch_bounds__(256) void spmm128_kernel(
    const int* __restrict__ ptrv, const int* __restrict__ srcs, const float* __restrict__ vals,
    const float* __restrict__ dg, const float* __restrict__ x, const float* __restrict__ z,
    float* __restrict__ y, int N, float alpha, float beta){
  int t = threadIdx.x;
  int g = t >> 5, lane = t & 31;
  int node = blockIdx.x*8 + g;
  if (node >= N) return;
  int e0 = ptrv[node], e1 = ptrv[node+1];
  const float4* x4 = (const float4*)x;
  float4 acc = make_float4(0.f,0.f,0.f,0.f);
  for (int eb = e0; eb < e1; eb += 8){
    int j = eb + (lane & 7);
    int s = srcs[j]; float v = vals[j];
    #pragma unroll
    for (int q = 0; q < 8; ++q){
      int   sq = __shfl(s, q, 32);
      float vq = __shfl(v, q, 32);
      float4 xv = x4[(size_t)sq*32 + lane];
      acc.x = fmaf(vq, xv.x, acc.x);
      acc.y = fmaf(vq, xv.y, acc.y);
      acc.z = fmaf(vq, xv.z, acc.z);
      acc.w = fmaf(vq, xv.w, acc.w);
    }
  }
  size_t ii = (size_t)node*32 + lane;
  float dgn = dg[node];
  float4 xi = x4[ii];
  float4 r;
  r.x = alpha*(acc.x + dgn*xi.x);
  r.y = alpha*(acc.y + dgn*xi.y);
  r.z = alpha*(acc.z + dgn*xi.z);
  r.w = alpha*(acc.w + dgn*xi.w);
  if (z){
    float4 zi = ((const float4*)z)[ii];
    r.x = fmaf(beta, zi.x, r.x);
    r.y = fmaf(beta, zi.y, r.y);
    r.z = fmaf(beta, zi.z, r.z);
    r.w = fmaf(beta, zi.w, r.w);
  }
  ((float4*)y)[ii] = r;
}

__global__ __launch_bounds__(256) void spmm32_kernel(
    const int* __restrict__ ptrv, const int* __restrict__ srcs, const float* __restrict__ vals,
    const float* __restrict__ dg, const float* __restrict__ x, const float* __restrict__ z,
    float* __restrict__ y, int N, float alpha, float beta){
  int t = threadIdx.x;
  int g = t >> 3, lane = t & 7;
  int node = blockIdx.x*32 + g;
  if (node >= N) return;
  int e0 = ptrv[node], e1 = ptrv[node+1];
  const float4* x4 = (const float4*)x;
  float4 acc = make_float4(0.f,0.f,0.f,0.f);
  for (int eb = e0; eb < e1; eb += 8){
    int j = eb + lane;
    int s = srcs[j]; float v = vals[j];
    #pragma unroll
    for (int q = 0; q < 8; ++q){
      int   sq = __shfl(s, q, 8);
      float vq = __shfl(v, q, 8);
      float4 xv = x4[(size_t)sq*8 + lane];
      acc.x = fmaf(vq, xv.x, acc.x);
      acc.y = fmaf(vq, xv.y, acc.y);
      acc.z = fmaf(vq, xv.z, acc.z);
      acc.w = fmaf(vq, xv.w, acc.w);
    }
  }
  size_t ii = (size_t)node*8 + lane;
  float dgn = dg[node];
  float4 xi = x4[ii];
  float4 r;
  r.x = alpha*(acc.x + dgn*xi.x);
  r.y = alpha*(acc.y + dgn*xi.y);
  r.z = alpha*(acc.z + dgn*xi.z);
  r.w = alpha*(acc.w + dgn*xi.w);
  if (z){
    float4 zi = ((const float4*)z)[ii];
    r.x = fmaf(beta, zi.x, r.x);
    r.y = fmaf(beta, zi.y, r.y);
    r.z = fmaf(beta, zi.z, r.z);
    r.w = fmaf(beta, zi.w, r.w);
  }
  ((float4*)y)[ii] = r;
}

// ---------------- fused: th2 = 2*(L HRb) - HRb  +  gateB GRU update ---------
__global__ __launch_bounds__(256) void spmm_gateB_kernel(
    const int* __restrict__ ptrv, const int* __restrict__ srcs, const float* __restrict__ vals,
    const float* __restrict__ dg, const float* __restrict__ th1, const float* __restrict__ HRb,
    const float* __restrict__ Whh, const float* __restrict__ bhh,
    const float* __restrict__ Zb, const float* __restrict__ gx2b,
    float* __restrict__ H, int N){
  __shared__ float sp[8][3][128];
  __shared__ float sW[3072];
  int t = threadIdx.x;
  int g = t >> 5, lane = t & 31;
  int node = blockIdx.x*8 + g;
  bool valid = (node < N);
  if (!valid) node = N-1;
  for (int idx = t; idx < 3072; idx += 256) sW[idx] = Whh[idx];
  size_t ii = (size_t)node*32 + lane;
  const float4* x4 = (const float4*)th1;
  const float4* z4 = (const float4*)HRb;
  float4 Zv   = ((const float4*)Zb)[ii];
  float4 Gx   = ((const float4*)gx2b)[ii];
  float4 Hold = ((const float4*)H)[ii];
  float4 zi   = z4[ii];
  int e0 = ptrv[node], e1 = ptrv[node+1];
  float4 acc = make_float4(0.f,0.f,0.f,0.f);
  for (int eb = e0; eb < e1; eb += 8){
    int j = eb + (lane & 7);
    int s = srcs[j]; float v = vals[j];
    #pragma unroll
    for (int q = 0; q < 8; ++q){
      int   sq = __shfl(s, q, 32);
      float vq = __shfl(v, q, 32);
      float4 xv = x4[(size_t)sq*32 + lane];
      acc.x = fmaf(vq, xv.x, acc.x);
      acc.y = fmaf(vq, xv.y, acc.y);
      acc.z = fmaf(vq, xv.z, acc.z);
      acc.w = fmaf(vq, xv.w, acc.w);
    }
  }
  float dgn = dg[node];
  float4 xi = x4[ii];
  float4 p2;
  p2.x = 2.f*(acc.x + dgn*xi.x) - zi.x;
  p2.y = 2.f*(acc.y + dgn*xi.y) - zi.y;
  p2.z = 2.f*(acc.z + dgn*xi.z) - zi.z;
  p2.w = 2.f*(acc.w + dgn*xi.w) - zi.w;
  ((float4*)&sp[g][0][0])[lane] = zi;
  ((float4*)&sp[g][1][0])[lane] = xi;
  ((float4*)&sp[g][2][0])[lane] = p2;
  __syncthreads();
  int bb8 = lane >> 3;
  const float4* W4 = (const float4*)sW;
  float4 bv = ((const float4*)bhh)[lane & 7];
  float gh0 = bv.x, gh1 = bv.y, gh2 = bv.z, gh3 = bv.w;
  #pragma unroll 1
  for (int k = 0; k < 3; ++k){
    const float* pk = &sp[g][k][bb8*32];
    #pragma unroll
    for (int o = 0; o < 32; o += 4){
      float4 pv = *reinterpret_cast<const float4*>(pk + o);
      #pragma unroll
      for (int oo = 0; oo < 4; ++oo){
        float p = reinterpret_cast<const float*>(&pv)[oo];
        float4 wv = W4[k*256 + (o+oo)*8 + (lane & 7)];
        gh0 = fmaf(p, wv.x, gh0);
        gh1 = fmaf(p, wv.y, gh1);
        gh2 = fmaf(p, wv.z, gh2);
        gh3 = fmaf(p, wv.w, gh3);
      }
    }
  }
  if (valid){
    float4 Hn;
    float Ht;
    Ht = tanhf(Gx.x + gh0); Hn.x = Zv.x*Hold.x + (1.f - Zv.x)*Ht;
    Ht = tanhf(Gx.y + gh1); Hn.y = Zv.y*Hold.y + (1.f - Zv.y)*Ht;
    Ht = tanhf(Gx.z + gh2); Hn.z = Zv.z*Hold.z + (1.f - Zv.z)*Ht;
    Ht = tanhf(Gx.w + gh3); Hn.w = Zv.w*Hold.w + (1.f - Zv.w)*Ht;
    ((float4*)H)[ii] = Hn;
  }
}

// ---------------- transpose layer-0 input ----------------
__global__ void transpose_x_kernel(const float* __restrict__ in, float* __restrict__ out,
                                   int N, int t){
  int idx = blockIdx.x*blockDim.x + threadIdx.x;   // over N*32
  if (idx >= N*32) return;
  int n = idx >> 5; int r = idx & 31; int b = r >> 3; int i = r & 7;
  out[idx] = in[(((size_t)b*12 + t)*N + n)*8 + i];
}

// ---------------- gate A (register-tiled GEMM; R12: nt act loads) ----------
template<int FIN>
__global__ __launch_bounds__(256) void gateA_kernel(
    const float* __restrict__ x0, const float* __restrict__ x1, const float* __restrict__ x2,
    const float* __restrict__ h0, const float* __restrict__ h1, const float* __restrict__ h2,
    const float* __restrict__ Wx, const float* __restrict__ bx,
    const float* __restrict__ Wh, const float* __restrict__ bh,
    float* __restrict__ Zb, float* __restrict__ gx2b, float* __restrict__ HRb, int M){
  int t = threadIdx.x;
  int h = t & 31, ty = t >> 5;
  int row0 = blockIdx.x*64 + ty*8;
  if (row0 >= M) return;
  bool full = (row0 + 8 <= M);

  float ag0[8]={0,0,0,0,0,0,0,0}, ag1[8]={0,0,0,0,0,0,0,0}, ag2[8]={0,0,0,0,0,0,0,0};
  float az[8]={0,0,0,0,0,0,0,0}, ar[8]={0,0,0,0,0,0,0,0};

  const float* xm[3] = {x0, x1, x2};
  const float* hm[3] = {h0, h1, h2};
  const int gstride = 3*FIN*32;

  #pragma unroll 1
  for (int k3 = 0; k3 < 3; ++k3){
    const float* Ak = xm[k3];
    const float* wb = Wx + k3*FIN*32 + h;
    #pragma unroll 1
    for (int k = 0; k < FIN; k += 4){
      nt_f4 a4[8];
      #pragma unroll
      for (int r = 0; r < 8; ++r){
        int rr = row0 + r; if (!full && rr >= M) rr = M-1;
        a4[r] = __builtin_nontemporal_load(
                  reinterpret_cast<const nt_f4*>(Ak + (size_t)rr*FIN + k));
      }
      #pragma unroll
      for (int kk = 0; kk < 4; ++kk){
        float w0 = wb[(k+kk)*32];
        float w1 = wb[(size_t)gstride   + (k+kk)*32];
        float w2 = wb[(size_t)gstride*2 + (k+kk)*32];
        #pragma unroll
        for (int r = 0; r < 8; ++r){
          float av = a4[r][kk];
          ag0[r] = fmaf(av, w0, ag0[r]);
          ag1[r] = fmaf(av, w1, ag1[r]);
          ag2[r] = fmaf(av, w2, ag2[r]);
        }
      }
    }
  }

  #pragma unroll 1
  for (int k3 = 0; k3 < 3; ++k3){
    const float* Ak = hm[k3];
    const float* wbz = Wh + k3*1024 + h;          // Wh[0][k3][o][h]
    #pragma unroll 1
    for (int k = 0; k < 32; k += 4){
      nt_f4 a4[8];
      #pragma unroll
      for (int r = 0; r < 8; ++r){
        int rr = row0 + r; if (!full && rr >= M) rr = M-1;
        a4[r] = __builtin_nontemporal_load(
                  reinterpret_cast<const nt_f4*>(Ak + (size_t)rr*32 + k));
      }
      #pragma unroll
      for (int kk = 0; kk < 4; ++kk){
        float wz = wbz[(k+kk)*32];
        float wr = wbz[3072 + (k+kk)*32];
        #pragma unroll
        for (int r = 0; r < 8; ++r){
          float av = a4[r][kk];
          az[r] = fmaf(av, wz, az[r]);
          ar[r] = fmaf(av, wr, ar[r]);
        }
      }
    }
  }

  float b0 = bx[h], b1 = bx[32+h], b2 = bx[64+h];
  float bz = bh[h], br = bh[32+h];
  #pragma unroll
  for (int r = 0; r < 8; ++r){
    int rr = row0 + r; if (rr >= M) break;
    float Z = sigmoidf_(ag0[r] + b0 + az[r] + bz);
    float R = sigmoidf_(ag1[r] + b1 + ar[r] + br);
    size_t ix = (size_t)rr*32 + h;
    Zb[ix]   = Z;
    gx2b[ix] = ag2[r] + b2;
    HRb[ix]  = h0[ix] * R;
  }
}

// ---------------- readout ----------------
__global__ void readout_kernel(const float* __restrict__ H1, const float* __restrict__ muW,
                               const float* __restrict__ mub, const float* __restrict__ sgW,
                               const float* __restrict__ sgb, float* __restrict__ outp, int N){
  int idx = blockIdx.x*blockDim.x + threadIdx.x;   // over 4*N
  if (idx >= 4*N) return;
  int b = idx / N, n = idx - b*N;
  const float* h = H1 + (size_t)n*128 + b*32;
  float m0 = mub[0], m1 = mub[1], s0 = sgb[0], s1 = sgb[1];
  #pragma unroll
  for (int o = 0; o < 32; ++o){
    float v = h[o];
    m0 = fmaf(v, muW[o*2+0], m0);
    m1 = fmaf(v, muW[o*2+1], m1);
    s0 = fmaf(v, sgW[o*2+0], s0);
    s1 = fmaf(v, sgW[o*2+1], s1);
  }
  size_t base = (size_t)(b*N + n)*2;
  outp[base]   = sigmoidf_(m0);
  outp[base+1] = sigmoidf_(m1);
  size_t sb = (size_t)8*N + base;
  outp[sb]   = (s0 > 15.f) ? s0 : log1pf(__expf(s0));
  outp[sb+1] = (s1 > 15.f) ? s1 : log1pf(__expf(s1));
}

__global__ void mean_kernel(const float* __restrict__ H1, float* __restrict__ mixsum, int N){
  int t = threadIdx.x;   // 128 = (b,o)
  int chunk = (N + gridDim.x - 1) / gridDim.x;
  int n0 = blockIdx.x*chunk, n1 = min(N, n0 + chunk);
  float acc = 0.f;
  for (int n = n0; n < n1; ++n) acc += H1[(size_t)n*128 + t];
  atomicAdd(mixsum + t, acc);
}

__global__ void softmax_kernel(const float* __restrict__ mixsum, float* __restrict__ outp,
                               float invN){
  __shared__ float v[128];
  __shared__ float e[128];
  int t = threadIdx.x; int b = t >> 5;
  float m = mixsum[t]*invN;
  v[t] = m; __syncthreads();
  float mx = -1e30f;
  for (int o = 0; o < 32; ++o) mx = fmaxf(mx, v[b*32 + o]);
  float ex = __expf(m - mx);
  e[t] = ex; __syncthreads();
  float s = 0.f;
  for (int o = 0; o < 32; ++o) s += e[b*32 + o];
  outp[t] = ex / s;
}

// ---------------------------------------------------------------------------

extern "C" void kernel_launch(void* const* d_in, const int* in_sizes, int n_in,
                              void* d_out, int out_size, void* d_ws, size_t ws_size,
                              hipStream_t stream){
  const float* in0  = (const float*)d_in[0];
  const void*  eidx = d_in[1];
  const float* ew   = (const float*)d_in[2];
  const float* Wx0  = (const float*)d_in[3];
  const float* Wh0  = (const float*)d_in[4];
  const float* bx0  = (const float*)d_in[5];
  const float* bh0  = (const float*)d_in[6];
  const float* Wx1  = (const float*)d_in[7];
  const float* Wh1  = (const float*)d_in[8];
  const float* bx1  = (const float*)d_in[9];
  const float* bh1  = (const float*)d_in[10];
  const float* muW  = (const float*)d_in[11];
  const float* mub  = (const float*)d_in[12];
  const float* sgW  = (const float*)d_in[13];
  const float* sgb  = (const float*)d_in[14];
  float* outp = (float*)d_out;

  const int N = in_sizes[0] / (4*12*8);
  const int E = in_sizes[1] / 2;
  const int M = 4*N;
  const int EP = E + 8*N;        // padded-edge capacity

  // ---- carve workspace ----
  char* w = (char*)d_ws;
  size_t off = 0;
  auto alloc = [&](size_t bytes)->void*{
    void* p = w + off;
    off += (bytes + 255) & ~(size_t)255;
    return p;
  };
  int*   row32   = (int*)  alloc((size_t)E*4);
  int*   col32   = (int*)  alloc((size_t)E*4);
  int*   csr_src = (int*)  alloc((size_t)EP*4);
  float* csr_val = (float*)alloc((size_t)EP*4);
  int*   ptrv    = (int*)  alloc((size_t)(N+1)*4);
  int*   cnt     = (int*)  alloc((size_t)N*4);
  int*   cnt2    = (int*)  alloc((size_t)N*4);
  float* deg     = (float*)alloc((size_t)N*4);
  float* dinv    = (float*)alloc((size_t)N*4);
  float* dgv     = (float*)alloc((size_t)N*4);
  int*   flag    = (int*)  alloc(256);
  float* mixsum  = (float*)alloc(512);
  float* xb0     = (float*)alloc((size_t)N*32*4);
  float* xb1     = (float*)alloc((size_t)N*128*4);  // basis(H0) cache T1 (written by L1)
  float* xb2     = (float*)alloc((size_t)N*128*4);  // basis(H0) cache T2
  float* th1     = (float*)alloc((size_t)N*128*4);  // scratch; low 12.8MB doubles as L0 x-basis
  float* th2     = (float*)alloc((size_t)N*128*4);
  float* Zb      = (float*)alloc((size_t)N*128*4);
  float* gx2b    = (float*)alloc((size_t)N*128*4);
  float* HRb     = (float*)alloc((size_t)N*128*4);
  float* H0      = (float*)alloc((size_t)N*128*4);
  float* H1      = (float*)alloc((size_t)N*128*4);
  float* xb1s = th1;                 // [N][32]
  float* xb2s = th1 + (size_t)N*32;  // [N][32]

  // ---- zero-init (ws is poisoned 0xAA before each call) ----
  (void)hipMemsetAsync(flag,   0, 4, stream);
  (void)hipMemsetAsync(deg,    0, (size_t)N*4, stream);
  (void)hipMemsetAsync(cnt,    0, (size_t)N*4, stream);
  (void)hipMemsetAsync(cnt2,   0, (size_t)N*4, stream);
  (void)hipMemsetAsync(H0,     0, (size_t)N*128*4, stream);
  (void)hipMemsetAsync(H1,     0, (size_t)N*128*4, stream);
  (void)hipMemsetAsync(xb1,    0, (size_t)N*128*4, stream);  // basis(H0=0) = 0 at t=0
  (void)hipMemsetAsync(xb2,    0, (size_t)N*128*4, stream);
  (void)hipMemsetAsync(mixsum, 0, 512, stream);

  // ---- preprocessing: dtype detect, degrees, padded CSR build ----
  {
    int ndw = 4096;
    if (ndw > 2*E) ndw = 2*E;
    int nthread = ndw/2 + 1;
    detect_kernel<<<(nthread+255)/256, 256, 0, stream>>>((const unsigned*)eidx, ndw, flag);
  }
  convert_kernel<<<(E+255)/256, 256, 0, stream>>>(eidx, ew, E, flag, row32, col32, deg, cnt);
  node_prep_kernel<<<(N+255)/256, 256, 0, stream>>>(deg, dinv, dgv, N);
  scan_kernel<<<1, 1024, 0, stream>>>(cnt, ptrv, N);
  fill_kernel<<<(E+255)/256, 256, 0, stream>>>(row32, col32, ew, dinv, ptrv, cnt2,
                                               csr_src, csr_val, E);
  pad_kernel<<<(N+255)/256, 256, 0, stream>>>(cnt, ptrv, csr_src, csr_val, N);

  const int g128 = (N+7)/8;    // spmm128 / fused: 8 nodes / 256 threads
  const int g32  = (N+31)/32;  // spmm32: 32 nodes / 256 threads
  const int gG   = (M+63)/64;  // gateA: 64 rows / 256 threads

  for (int t = 0; t < 12; ++t){
    // ===== layer 0 (Fin=8); h-basis read from cache (xb1, xb2) =====
    transpose_x_kernel<<<(N*32+255)/256, 256, 0, stream>>>(in0, xb0, N, t);
    spmm32_kernel<<<g32,256,0,stream>>>(ptrv,csr_src,csr_val,dgv, xb0,nullptr,xb1s, N, 1.f, 0.f);
    spmm32_kernel<<<g32,256,0,stream>>>(ptrv,csr_src,csr_val,dgv, xb1s,xb0,  xb2s, N, 2.f,-1.f);
    gateA_kernel<8><<<gG,256,0,stream>>>(xb0,xb1s,xb2s, H0,xb1,xb2,
                                         Wx0,bx0, Wh0,bh0, Zb,gx2b,HRb, M);
    spmm128_kernel<<<g128,256,0,stream>>>(ptrv,csr_src,csr_val,dgv, HRb,nullptr,th1, N, 1.f, 0.f);
    spmm_gateB_kernel<<<g128,256,0,stream>>>(ptrv,csr_src,csr_val,dgv, th1,HRb,
                                             Wh0+6144, bh0+64, Zb,gx2b, H0, N);

    // ===== layer 1 (Fin=32, x = H0); x-basis -> cache (xb1, xb2) =====
    spmm128_kernel<<<g128,256,0,stream>>>(ptrv,csr_src,csr_val,dgv, H0,nullptr,xb1, N, 1.f, 0.f);
    spmm128_kernel<<<g128,256,0,stream>>>(ptrv,csr_src,csr_val,dgv, xb1,H0,   xb2, N, 2.f,-1.f);
    spmm128_kernel<<<g128,256,0,stream>>>(ptrv,csr_src,csr_val,dgv, H1,nullptr,th1, N, 1.f, 0.f);
    spmm128_kernel<<<g128,256,0,stream>>>(ptrv,csr_src,csr_val,dgv, th1,H1,   th2, N, 2.f,-1.f);
    gateA_kernel<32><<<gG,256,0,stream>>>(H0,xb1,xb2, H1,th1,th2,
                                          Wx1,bx1, Wh1,bh1, Zb,gx2b,HRb, M);
    spmm128_kernel<<<g128,256,0,stream>>>(ptrv,csr_src,csr_val,dgv, HRb,nullptr,th1, N, 1.f, 0.f);
    spmm_gateB_kernel<<<g128,256,0,stream>>>(ptrv,csr_src,csr_val,dgv, th1,HRb,
                                             Wh1+6144, bh1+64, Zb,gx2b, H1, N);
  }

  // ---- readout ----
  readout_kernel<<<(4*N+255)/256, 256, 0, stream>>>(H1, muW, mub, sgW, sgb, outp, N);
  mean_kernel<<<256, 128, 0, stream>>>(H1, mixsum, N);
  softmax_kernel<<<1, 128, 0, stream>>>(mixsum, outp + (size_t)16*N, 1.0f/(float)N);
}

// Round 13
// 10995.559 us; speedup vs baseline: 1.2727x; 1.2727x over previous
//
#include <hip/hip_runtime.h>
#include <cstdint>
#include <cstddef>

// ---------------------------------------------------------------------------
// GConvGRU (ChebConv K=3, 2 layers) + readout, for MI355X.
// R13: R10 base (nt loads reverted — R12 showed acts are L1-broadcast-reused;
//      nt forced them to HBM, FETCH 76->297MB). ONE change: gateA stages all
//      six 64-row act panels in LDS (coalesced, single barrier); K-loop act
//      reads become LDS broadcasts, only weight loads stay on VMEM pipe.
// ---------------------------------------------------------------------------

__device__ __forceinline__ float sigmoidf_(float x){ return 1.f/(1.f+__expf(-x)); }

// ---------------- preprocessing ----------------

__global__ void detect_kernel(const unsigned* __restrict__ buf, int ndw, int* flag){
  int i = blockIdx.x*blockDim.x + threadIdx.x;
  int j = 2*i + 1;
  if (j < ndw && buf[j] != 0u) atomicOr(flag, 1);   // flag=1 -> int32
}

__global__ void convert_kernel(const void* __restrict__ eidx, const float* __restrict__ w,
                               int E, const int* __restrict__ flag,
                               int* __restrict__ row32, int* __restrict__ col32,
                               float* __restrict__ deg, int* __restrict__ cnt){
  int e = blockIdx.x*blockDim.x + threadIdx.x;
  if (e >= E) return;
  int r, c;
  if (*flag){ const int* p = (const int*)eidx; r = p[e]; c = p[E+e]; }
  else { const long long* p = (const long long*)eidx; r = (int)p[e]; c = (int)p[(size_t)E+e]; }
  row32[e] = r; col32[e] = c;
  atomicAdd(deg + r, w[e]);
  atomicAdd(cnt + c, 1);
}

__global__ void node_prep_kernel(const float* __restrict__ deg, float* __restrict__ dinv,
                                 float* __restrict__ dg, int N){
  int n = blockIdx.x*blockDim.x + threadIdx.x;
  if (n >= N) return;
  float d = deg[n];
  if (d > 0.f){ dinv[n] = rsqrtf(d); dg[n] = 0.f; }
  else        { dinv[n] = 0.f;       dg[n] = -1.f; }
}

// Exclusive scan of PADDED counts ((cnt+7)&~7) -> ptr[N+1]. 1 block, 1024 thr.
__global__ void scan_kernel(const int* __restrict__ cnt, int* __restrict__ ptrout, int N){
  __shared__ int s[1024];
  int t = threadIdx.x;
  int chunk = (N + 1023) / 1024;
  int a0 = t*chunk, a1 = min(N, a0 + chunk);
  int sum = 0;
  for (int i = a0; i < a1; ++i) sum += (cnt[i]+7)&~7;
  s[t] = sum; __syncthreads();
  for (int off = 1; off < 1024; off <<= 1){
    int v = (t >= off) ? s[t-off] : 0;
    __syncthreads();
    s[t] += v;
    __syncthreads();
  }
  int run = (t == 0) ? 0 : s[t-1];
  for (int i = a0; i < a1; ++i){ ptrout[i] = run; run += (cnt[i]+7)&~7; }
  if (t == 1023) ptrout[N] = s[1023];
}

__global__ void fill_kernel(const int* __restrict__ row32, const int* __restrict__ col32,
                            const float* __restrict__ w, const float* __restrict__ dinv,
                            const int* __restrict__ ptrv, int* __restrict__ cnt2,
                            int* __restrict__ srcs, float* __restrict__ vals, int E){
  int e = blockIdx.x*blockDim.x + threadIdx.x;
  if (e >= E) return;
  int r = row32[e], c = col32[e];
  int p = ptrv[c] + atomicAdd(cnt2 + c, 1);
  srcs[p] = r;
  vals[p] = -w[e] * dinv[r] * dinv[c];
}

// Pad slots gather (src=0, val=0): bit-identical arithmetic, L2-hot row.
__global__ void pad_kernel(const int* __restrict__ cnt, const int* __restrict__ ptrv,
                           int* __restrict__ srcs, float* __restrict__ vals, int N){
  int n = blockIdx.x*blockDim.x + threadIdx.x;
  if (n >= N) return;
  int base = ptrv[n];
  int real = cnt[n];
  int padded = ptrv[n+1] - base;
  for (int j = real; j < padded; ++j){ srcs[base+j] = 0; vals[base+j] = 0.f; }
}

// ---------------- SpMM: y = alpha*(A x + diag*x) + beta*z ----------------
__global__ __launch_bounds__(256) void spmm128_kernel(
    const int* __restrict__ ptrv, const int* __restrict__ srcs, const float* __restrict__ vals,
    const float* __restrict__ dg, const float* __restrict__ x, const float* __restrict__ z,
    float* __restrict__ y, int N, float alpha, float beta){
  int t = threadIdx.x;
  int g = t >> 5, lane = t & 31;
  int node = blockIdx.x*8 + g;
  if (node >= N) return;
  int e0 = ptrv[node], e1 = ptrv[node+1];
  const float4* x4 = (const float4*)x;
  float4 acc = make_float4(0.f,0.f,0.f,0.f);
  for (int eb = e0; eb < e1; eb += 8){
    int j = eb + (lane & 7);
    int s = srcs[j]; float v = vals[j];
    #pragma unroll
    for (int q = 0; q < 8; ++q){
      int   sq = __shfl(s, q, 32);
      float vq = __shfl(v, q, 32);
      float4 xv = x4[(size_t)sq*32 + lane];
      acc.x = fmaf(vq, xv.x, acc.x);
      acc.y = fmaf(vq, xv.y, acc.y);
      acc.z = fmaf(vq, xv.z, acc.z);
      acc.w = fmaf(vq, xv.w, acc.w);
    }
  }
  size_t ii = (size_t)node*32 + lane;
  float dgn = dg[node];
  float4 xi = x4[ii];
  float4 r;
  r.x = alpha*(acc.x + dgn*xi.x);
  r.y = alpha*(acc.y + dgn*xi.y);
  r.z = alpha*(acc.z + dgn*xi.z);
  r.w = alpha*(acc.w + dgn*xi.w);
  if (z){
    float4 zi = ((const float4*)z)[ii];
    r.x = fmaf(beta, zi.x, r.x);
    r.y = fmaf(beta, zi.y, r.y);
    r.z = fmaf(beta, zi.z, r.z);
    r.w = fmaf(beta, zi.w, r.w);
  }
  ((float4*)y)[ii] = r;
}

__global__ __launch_bounds__(256) void spmm32_kernel(
    const int* __restrict__ ptrv, const int* __restrict__ srcs, const float* __restrict__ vals,
    const float* __restrict__ dg, const float* __restrict__ x, const float* __restrict__ z,
    float* __restrict__ y, int N, float alpha, float beta){
  int t = threadIdx.x;
  int g = t >> 3, lane = t & 7;
  int node = blockIdx.x*32 + g;
  if (node >= N) return;
  int e0 = ptrv[node], e1 = ptrv[node+1];
  const float4* x4 = (const float4*)x;
  float4 acc = make_float4(0.f,0.f,0.f,0.f);
  for (int eb = e0; eb < e1; eb += 8){
    int j = eb + lane;
    int s = srcs[j]; float v = vals[j];
    #pragma unroll
    for (int q = 0; q < 8; ++q){
      int   sq = __shfl(s, q, 8);
      float vq = __shfl(v, q, 8);
      float4 xv = x4[(size_t)sq*8 + lane];
      acc.x = fmaf(vq, xv.x, acc.x);
      acc.y = fmaf(vq, xv.y, acc.y);
      acc.z = fmaf(vq, xv.z, acc.z);
      acc.w = fmaf(vq, xv.w, acc.w);
    }
  }
  size_t ii = (size_t)node*8 + lane;
  float dgn = dg[node];
  float4 xi = x4[ii];
  float4 r;
  r.x = alpha*(acc.x + dgn*xi.x);
  r.y = alpha*(acc.y + dgn*xi.y);
  r.z = alpha*(acc.z + dgn*xi.z);
  r.w = alpha*(acc.w + dgn*xi.w);
  if (z){
    float4 zi = ((const float4*)z)[ii];
    r.x = fmaf(beta, zi.x, r.x);
    r.y = fmaf(beta, zi.y, r.y);
    r.z = fmaf(beta, zi.z, r.z);
    r.w = fmaf(beta, zi.w, r.w);
  }
  ((float4*)y)[ii] = r;
}

// ---------------- fused: th2 = 2*(L HRb) - HRb  +  gateB GRU update ---------
__global__ __launch_bounds__(256) void spmm_gateB_kernel(
    const int* __restrict__ ptrv, const int* __restrict__ srcs, const float* __restrict__ vals,
    const float* __restrict__ dg, const float* __restrict__ th1, const float* __restrict__ HRb,
    const float* __restrict__ Whh, const float* __restrict__ bhh,
    const float* __restrict__ Zb, const float* __restrict__ gx2b,
    float* __restrict__ H, int N){
  __shared__ float sp[8][3][128];
  __shared__ float sW[3072];
  int t = threadIdx.x;
  int g = t >> 5, lane = t & 31;
  int node = blockIdx.x*8 + g;
  bool valid = (node < N);
  if (!valid) node = N-1;
  for (int idx = t; idx < 3072; idx += 256) sW[idx] = Whh[idx];
  size_t ii = (size_t)node*32 + lane;
  const float4* x4 = (const float4*)th1;
  const float4* z4 = (const float4*)HRb;
  float4 Zv   = ((const float4*)Zb)[ii];
  float4 Gx   = ((const float4*)gx2b)[ii];
  float4 Hold = ((const float4*)H)[ii];
  float4 zi   = z4[ii];
  int e0 = ptrv[node], e1 = ptrv[node+1];
  float4 acc = make_float4(0.f,0.f,0.f,0.f);
  for (int eb = e0; eb < e1; eb += 8){
    int j = eb + (lane & 7);
    int s = srcs[j]; float v = vals[j];
    #pragma unroll
    for (int q = 0; q < 8; ++q){
      int   sq = __shfl(s, q, 32);
      float vq = __shfl(v, q, 32);
      float4 xv = x4[(size_t)sq*32 + lane];
      acc.x = fmaf(vq, xv.x, acc.x);
      acc.y = fmaf(vq, xv.y, acc.y);
      acc.z = fmaf(vq, xv.z, acc.z);
      acc.w = fmaf(vq, xv.w, acc.w);
    }
  }
  float dgn = dg[node];
  float4 xi = x4[ii];
  float4 p2;
  p2.x = 2.f*(acc.x + dgn*xi.x) - zi.x;
  p2.y = 2.f*(acc.y + dgn*xi.y) - zi.y;
  p2.z = 2.f*(acc.z + dgn*xi.z) - zi.z;
  p2.w = 2.f*(acc.w + dgn*xi.w) - zi.w;
  ((float4*)&sp[g][0][0])[lane] = zi;
  ((float4*)&sp[g][1][0])[lane] = xi;
  ((float4*)&sp[g][2][0])[lane] = p2;
  __syncthreads();
  int bb8 = lane >> 3;
  const float4* W4 = (const float4*)sW;
  float4 bv = ((const float4*)bhh)[lane & 7];
  float gh0 = bv.x, gh1 = bv.y, gh2 = bv.z, gh3 = bv.w;
  #pragma unroll 1
  for (int k = 0; k < 3; ++k){
    const float* pk = &sp[g][k][bb8*32];
    #pragma unroll
    for (int o = 0; o < 32; o += 4){
      float4 pv = *reinterpret_cast<const float4*>(pk + o);
      #pragma unroll
      for (int oo = 0; oo < 4; ++oo){
        float p = reinterpret_cast<const float*>(&pv)[oo];
        float4 wv = W4[k*256 + (o+oo)*8 + (lane & 7)];
        gh0 = fmaf(p, wv.x, gh0);
        gh1 = fmaf(p, wv.y, gh1);
        gh2 = fmaf(p, wv.z, gh2);
        gh3 = fmaf(p, wv.w, gh3);
      }
    }
  }
  if (valid){
    float4 Hn;
    float Ht;
    Ht = tanhf(Gx.x + gh0); Hn.x = Zv.x*Hold.x + (1.f - Zv.x)*Ht;
    Ht = tanhf(Gx.y + gh1); Hn.y = Zv.y*Hold.y + (1.f - Zv.y)*Ht;
    Ht = tanhf(Gx.z + gh2); Hn.z = Zv.z*Hold.z + (1.f - Zv.z)*Ht;
    Ht = tanhf(Gx.w + gh3); Hn.w = Zv.w*Hold.w + (1.f - Zv.w)*Ht;
    ((float4*)H)[ii] = Hn;
  }
}

// ---------------- transpose layer-0 input ----------------
__global__ void transpose_x_kernel(const float* __restrict__ in, float* __restrict__ out,
                                   int N, int t){
  int idx = blockIdx.x*blockDim.x + threadIdx.x;   // over N*32
  if (idx >= N*32) return;
  int n = idx >> 5; int r = idx & 31; int b = r >> 3; int i = r & 7;
  out[idx] = in[(((size_t)b*12 + t)*N + n)*8 + i];
}

// ---------------- gate A: register-tiled GEMM, acts staged in LDS ----------
// 64 rows/block. All six act panels staged coalesced into LDS (one barrier);
// K-loop act reads are LDS broadcasts (free), weights stay global (L1-reused
// 8x across ty-groups). Store path reads H from the staged panel.
template<int FIN>
__global__ __launch_bounds__(256) void gateA_kernel(
    const float* __restrict__ x0, const float* __restrict__ x1, const float* __restrict__ x2,
    const float* __restrict__ h0, const float* __restrict__ h1, const float* __restrict__ h2,
    const float* __restrict__ Wx, const float* __restrict__ bx,
    const float* __restrict__ Wh, const float* __restrict__ bh,
    float* __restrict__ Zb, float* __restrict__ gx2b, float* __restrict__ HRb, int M){
  __shared__ float sx[3][64*FIN];
  __shared__ float sh[3][64*32];
  int t = threadIdx.x;
  int h = t & 31, ty = t >> 5;
  size_t base = (size_t)blockIdx.x*64;
  int row0 = (int)base + ty*8;

  // ---- stage acts (coalesced float4; source row clamped for generality) ----
  {
    const float* xm[3] = {x0, x1, x2};
    const float* hm[3] = {h0, h1, h2};
    constexpr int XF4 = FIN/4;          // float4s per x-row
    #pragma unroll
    for (int p = 0; p < 3; ++p){
      float4* dst = (float4*)sx[p];
      const float4* src = (const float4*)xm[p];
      for (int i = t; i < 64*XF4; i += 256){
        int rl = i / XF4, c = i - rl*XF4;
        size_t gr = base + rl; if (gr >= (size_t)M) gr = M-1;
        dst[i] = src[gr*XF4 + c];
      }
      float4* dsth = (float4*)sh[p];
      const float4* srch = (const float4*)hm[p];
      for (int i = t; i < 512; i += 256){
        int rl = i >> 3, c = i & 7;
        size_t gr = base + rl; if (gr >= (size_t)M) gr = M-1;
        dsth[i] = srch[gr*8 + c];
      }
    }
  }
  __syncthreads();
  if (row0 >= M) return;   // after barrier: safe

  float ag0[8]={0,0,0,0,0,0,0,0}, ag1[8]={0,0,0,0,0,0,0,0}, ag2[8]={0,0,0,0,0,0,0,0};
  float az[8]={0,0,0,0,0,0,0,0}, ar[8]={0,0,0,0,0,0,0,0};
  const int gstride = 3*FIN*32;

  // ---- x-part ----
  #pragma unroll 1
  for (int k3 = 0; k3 < 3; ++k3){
    const float* Ak = sx[k3];
    const float* wb = Wx + k3*FIN*32 + h;
    #pragma unroll 1
    for (int k = 0; k < FIN; k += 4){
      float4 a4[8];
      #pragma unroll
      for (int r = 0; r < 8; ++r)
        a4[r] = *reinterpret_cast<const float4*>(Ak + (ty*8 + r)*FIN + k);
      #pragma unroll
      for (int kk = 0; kk < 4; ++kk){
        float w0 = wb[(k+kk)*32];
        float w1 = wb[(size_t)gstride   + (k+kk)*32];
        float w2 = wb[(size_t)gstride*2 + (k+kk)*32];
        #pragma unroll
        for (int r = 0; r < 8; ++r){
          float av = reinterpret_cast<const float*>(&a4[r])[kk];
          ag0[r] = fmaf(av, w0, ag0[r]);
          ag1[r] = fmaf(av, w1, ag1[r]);
          ag2[r] = fmaf(av, w2, ag2[r]);
        }
      }
    }
  }

  // ---- h-part ----
  #pragma unroll 1
  for (int k3 = 0; k3 < 3; ++k3){
    const float* Ak = sh[k3];
    const float* wbz = Wh + k3*1024 + h;          // Wh[0][k3][o][h]
    #pragma unroll 1
    for (int k = 0; k < 32; k += 4){
      float4 a4[8];
      #pragma unroll
      for (int r = 0; r < 8; ++r)
        a4[r] = *reinterpret_cast<const float4*>(Ak + (ty*8 + r)*32 + k);
      #pragma unroll
      for (int kk = 0; kk < 4; ++kk){
        float wz = wbz[(k+kk)*32];
        float wr = wbz[3072 + (k+kk)*32];
        #pragma unroll
        for (int r = 0; r < 8; ++r){
          float av = reinterpret_cast<const float*>(&a4[r])[kk];
          az[r] = fmaf(av, wz, az[r]);
          ar[r] = fmaf(av, wr, ar[r]);
        }
      }
    }
  }

  float b0 = bx[h], b1 = bx[32+h], b2 = bx[64+h];
  float bz = bh[h], br = bh[32+h];
  #pragma unroll
  for (int r = 0; r < 8; ++r){
    int rr = row0 + r; if (rr >= M) break;
    float Z = sigmoidf_(ag0[r] + b0 + az[r] + bz);
    float R = sigmoidf_(ag1[r] + b1 + ar[r] + br);
    size_t ix = (size_t)rr*32 + h;
    Zb[ix]   = Z;
    gx2b[ix] = ag2[r] + b2;
    HRb[ix]  = sh[0][(ty*8 + r)*32 + h] * R;   // H from staged panel
  }
}

// ---------------- readout ----------------
__global__ void readout_kernel(const float* __restrict__ H1, const float* __restrict__ muW,
                               const float* __restrict__ mub, const float* __restrict__ sgW,
                               const float* __restrict__ sgb, float* __restrict__ outp, int N){
  int idx = blockIdx.x*blockDim.x + threadIdx.x;   // over 4*N
  if (idx >= 4*N) return;
  int b = idx / N, n = idx - b*N;
  const float* h = H1 + (size_t)n*128 + b*32;
  float m0 = mub[0], m1 = mub[1], s0 = sgb[0], s1 = sgb[1];
  #pragma unroll
  for (int o = 0; o < 32; ++o){
    float v = h[o];
    m0 = fmaf(v, muW[o*2+0], m0);
    m1 = fmaf(v, muW[o*2+1], m1);
    s0 = fmaf(v, sgW[o*2+0], s0);
    s1 = fmaf(v, sgW[o*2+1], s1);
  }
  size_t base = (size_t)(b*N + n)*2;
  outp[base]   = sigmoidf_(m0);
  outp[base+1] = sigmoidf_(m1);
  size_t sb = (size_t)8*N + base;
  outp[sb]   = (s0 > 15.f) ? s0 : log1pf(__expf(s0));
  outp[sb+1] = (s1 > 15.f) ? s1 : log1pf(__expf(s1));
}

__global__ void mean_kernel(const float* __restrict__ H1, float* __restrict__ mixsum, int N){
  int t = threadIdx.x;   // 128 = (b,o)
  int chunk = (N + gridDim.x - 1) / gridDim.x;
  int n0 = blockIdx.x*chunk, n1 = min(N, n0 + chunk);
  float acc = 0.f;
  for (int n = n0; n < n1; ++n) acc += H1[(size_t)n*128 + t];
  atomicAdd(mixsum + t, acc);
}

__global__ void softmax_kernel(const float* __restrict__ mixsum, float* __restrict__ outp,
                               float invN){
  __shared__ float v[128];
  __shared__ float e[128];
  int t = threadIdx.x; int b = t >> 5;
  float m = mixsum[t]*invN;
  v[t] = m; __syncthreads();
  float mx = -1e30f;
  for (int o = 0; o < 32; ++o) mx = fmaxf(mx, v[b*32 + o]);
  float ex = __expf(m - mx);
  e[t] = ex; __syncthreads();
  float s = 0.f;
  for (int o = 0; o < 32; ++o) s += e[b*32 + o];
  outp[t] = ex / s;
}

// ---------------------------------------------------------------------------

extern "C" void kernel_launch(void* const* d_in, const int* in_sizes, int n_in,
                              void* d_out, int out_size, void* d_ws, size_t ws_size,
                              hipStream_t stream){
  const float* in0  = (const float*)d_in[0];
  const void*  eidx = d_in[1];
  const float* ew   = (const float*)d_in[2];
  const float* Wx0  = (const float*)d_in[3];
  const float* Wh0  = (const float*)d_in[4];
  const float* bx0  = (const float*)d_in[5];
  const float* bh0  = (const float*)d_in[6];
  const float* Wx1  = (const float*)d_in[7];
  const float* Wh1  = (const float*)d_in[8];
  const float* bx1  = (const float*)d_in[9];
  const float* bh1  = (const float*)d_in[10];
  const float* muW  = (const float*)d_in[11];
  const float* mub  = (const float*)d_in[12];
  const float* sgW  = (const float*)d_in[13];
  const float* sgb  = (const float*)d_in[14];
  float* outp = (float*)d_out;

  const int N = in_sizes[0] / (4*12*8);
  const int E = in_sizes[1] / 2;
  const int M = 4*N;
  const int EP = E + 8*N;        // padded-edge capacity

  // ---- carve workspace ----
  char* w = (char*)d_ws;
  size_t off = 0;
  auto alloc = [&](size_t bytes)->void*{
    void* p = w + off;
    off += (bytes + 255) & ~(size_t)255;
    return p;
  };
  int*   row32   = (int*)  alloc((size_t)E*4);
  int*   col32   = (int*)  alloc((size_t)E*4);
  int*   csr_src = (int*)  alloc((size_t)EP*4);
  float* csr_val = (float*)alloc((size_t)EP*4);
  int*   ptrv    = (int*)  alloc((size_t)(N+1)*4);
  int*   cnt     = (int*)  alloc((size_t)N*4);
  int*   cnt2    = (int*)  alloc((size_t)N*4);
  float* deg     = (float*)alloc((size_t)N*4);
  float* dinv    = (float*)alloc((size_t)N*4);
  float* dgv     = (float*)alloc((size_t)N*4);
  int*   flag    = (int*)  alloc(256);
  float* mixsum  = (float*)alloc(512);
  float* xb0     = (float*)alloc((size_t)N*32*4);
  float* xb1     = (float*)alloc((size_t)N*128*4);  // basis(H0) cache T1 (written by L1)
  float* xb2     = (float*)alloc((size_t)N*128*4);  // basis(H0) cache T2
  float* th1     = (float*)alloc((size_t)N*128*4);  // scratch; low 12.8MB doubles as L0 x-basis
  float* th2     = (float*)alloc((size_t)N*128*4);
  float* Zb      = (float*)alloc((size_t)N*128*4);
  float* gx2b    = (float*)alloc((size_t)N*128*4);
  float* HRb     = (float*)alloc((size_t)N*128*4);
  float* H0      = (float*)alloc((size_t)N*128*4);
  float* H1      = (float*)alloc((size_t)N*128*4);
  float* xb1s = th1;                 // [N][32]
  float* xb2s = th1 + (size_t)N*32;  // [N][32]

  // ---- zero-init (ws is poisoned 0xAA before each call) ----
  (void)hipMemsetAsync(flag,   0, 4, stream);
  (void)hipMemsetAsync(deg,    0, (size_t)N*4, stream);
  (void)hipMemsetAsync(cnt,    0, (size_t)N*4, stream);
  (void)hipMemsetAsync(cnt2,   0, (size_t)N*4, stream);
  (void)hipMemsetAsync(H0,     0, (size_t)N*128*4, stream);
  (void)hipMemsetAsync(H1,     0, (size_t)N*128*4, stream);
  (void)hipMemsetAsync(xb1,    0, (size_t)N*128*4, stream);  // basis(H0=0) = 0 at t=0
  (void)hipMemsetAsync(xb2,    0, (size_t)N*128*4, stream);
  (void)hipMemsetAsync(mixsum, 0, 512, stream);

  // ---- preprocessing: dtype detect, degrees, padded CSR build ----
  {
    int ndw = 4096;
    if (ndw > 2*E) ndw = 2*E;
    int nthread = ndw/2 + 1;
    detect_kernel<<<(nthread+255)/256, 256, 0, stream>>>((const unsigned*)eidx, ndw, flag);
  }
  convert_kernel<<<(E+255)/256, 256, 0, stream>>>(eidx, ew, E, flag, row32, col32, deg, cnt);
  node_prep_kernel<<<(N+255)/256, 256, 0, stream>>>(deg, dinv, dgv, N);
  scan_kernel<<<1, 1024, 0, stream>>>(cnt, ptrv, N);
  fill_kernel<<<(E+255)/256, 256, 0, stream>>>(row32, col32, ew, dinv, ptrv, cnt2,
                                               csr_src, csr_val, E);
  pad_kernel<<<(N+255)/256, 256, 0, stream>>>(cnt, ptrv, csr_src, csr_val, N);

  const int g128 = (N+7)/8;    // spmm128 / fused: 8 nodes / 256 threads
  const int g32  = (N+31)/32;  // spmm32: 32 nodes / 256 threads
  const int gG   = (M+63)/64;  // gateA: 64 rows / 256 threads

  for (int t = 0; t < 12; ++t){
    // ===== layer 0 (Fin=8); h-basis read from cache (xb1, xb2) =====
    transpose_x_kernel<<<(N*32+255)/256, 256, 0, stream>>>(in0, xb0, N, t);
    spmm32_kernel<<<g32,256,0,stream>>>(ptrv,csr_src,csr_val,dgv, xb0,nullptr,xb1s, N, 1.f, 0.f);
    spmm32_kernel<<<g32,256,0,stream>>>(ptrv,csr_src,csr_val,dgv, xb1s,xb0,  xb2s, N, 2.f,-1.f);
    gateA_kernel<8><<<gG,256,0,stream>>>(xb0,xb1s,xb2s, H0,xb1,xb2,
                                         Wx0,bx0, Wh0,bh0, Zb,gx2b,HRb, M);
    spmm128_kernel<<<g128,256,0,stream>>>(ptrv,csr_src,csr_val,dgv, HRb,nullptr,th1, N, 1.f, 0.f);
    spmm_gateB_kernel<<<g128,256,0,stream>>>(ptrv,csr_src,csr_val,dgv, th1,HRb,
                                             Wh0+6144, bh0+64, Zb,gx2b, H0, N);

    // ===== layer 1 (Fin=32, x = H0); x-basis -> cache (xb1, xb2) =====
    spmm128_kernel<<<g128,256,0,stream>>>(ptrv,csr_src,csr_val,dgv, H0,nullptr,xb1, N, 1.f, 0.f);
    spmm128_kernel<<<g128,256,0,stream>>>(ptrv,csr_src,csr_val,dgv, xb1,H0,   xb2, N, 2.f,-1.f);
    spmm128_kernel<<<g128,256,0,stream>>>(ptrv,csr_src,csr_val,dgv, H1,nullptr,th1, N, 1.f, 0.f);
    spmm128_kernel<<<g128,256,0,stream>>>(ptrv,csr_src,csr_val,dgv, th1,H1,   th2, N, 2.f,-1.f);
    gateA_kernel<32><<<gG,256,0,stream>>>(H0,xb1,xb2, H1,th1,th2,
                                          Wx1,bx1, Wh1,bh1, Zb,gx2b,HRb, M);
    spmm128_kernel<<<g128,256,0,stream>>>(ptrv,csr_src,csr_val,dgv, HRb,nullptr,th1, N, 1.f, 0.f);
    spmm_gateB_kernel<<<g128,256,0,stream>>>(ptrv,csr_src,csr_val,dgv, th1,HRb,
                                             Wh1+6144, bh1+64, Zb,gx2b, H1, N);
  }

  // ---- readout ----
  readout_kernel<<<(4*N+255)/256, 256, 0, stream>>>(H1, muW, mub, sgW, sgb, outp, N);
  mean_kernel<<<256, 128, 0, stream>>>(H1, mixsum, N);
  softmax_kernel<<<1, 128, 0, stream>>>(mixsum, outp + (size_t)16*N, 1.0f/(float)N);
}

// Round 14
// 8208.448 us; speedup vs baseline: 1.7048x; 1.3395x over previous
//
#include <hip/hip_runtime.h>
#include <cstdint>
#include <cstddef>

// ---------------------------------------------------------------------------
// GConvGRU (ChebConv K=3, 2 layers) + readout, for MI355X.
// R14 (on R13, 11.0ms): spmm gathers are LLC-BW-bound (~52GB/call random rows
//   @ ~10.6 TB/s). Halve gather bytes: fp16 SHADOW copies of all gathered
//   matrices (H0,H1,HRb + one shared basis shadow s1h); gathers read 256B/row,
//   all arithmetic + own-row/epilogue/gate reads stay fp32. Writers emit both.
//   row32/col32 aliased into th2 (workspace ~293MB).
// ---------------------------------------------------------------------------

typedef _Float16 half4 __attribute__((ext_vector_type(4)));

__device__ __forceinline__ float sigmoidf_(float x){ return 1.f/(1.f+__expf(-x)); }

// ---------------- preprocessing ----------------

__global__ void detect_kernel(const unsigned* __restrict__ buf, int ndw, int* flag){
  int i = blockIdx.x*blockDim.x + threadIdx.x;
  int j = 2*i + 1;
  if (j < ndw && buf[j] != 0u) atomicOr(flag, 1);   // flag=1 -> int32
}

__global__ void convert_kernel(const void* __restrict__ eidx, const float* __restrict__ w,
                               int E, const int* __restrict__ flag,
                               int* __restrict__ row32, int* __restrict__ col32,
                               float* __restrict__ deg, int* __restrict__ cnt){
  int e = blockIdx.x*blockDim.x + threadIdx.x;
  if (e >= E) return;
  int r, c;
  if (*flag){ const int* p = (const int*)eidx; r = p[e]; c = p[E+e]; }
  else { const long long* p = (const long long*)eidx; r = (int)p[e]; c = (int)p[(size_t)E+e]; }
  row32[e] = r; col32[e] = c;
  atomicAdd(deg + r, w[e]);
  atomicAdd(cnt + c, 1);
}

__global__ void node_prep_kernel(const float* __restrict__ deg, float* __restrict__ dinv,
                                 float* __restrict__ dg, int N){
  int n = blockIdx.x*blockDim.x + threadIdx.x;
  if (n >= N) return;
  float d = deg[n];
  if (d > 0.f){ dinv[n] = rsqrtf(d); dg[n] = 0.f; }
  else        { dinv[n] = 0.f;       dg[n] = -1.f; }
}

// Exclusive scan of PADDED counts ((cnt+7)&~7) -> ptr[N+1]. 1 block, 1024 thr.
__global__ void scan_kernel(const int* __restrict__ cnt, int* __restrict__ ptrout, int N){
  __shared__ int s[1024];
  int t = threadIdx.x;
  int chunk = (N + 1023) / 1024;
  int a0 = t*chunk, a1 = min(N, a0 + chunk);
  int sum = 0;
  for (int i = a0; i < a1; ++i) sum += (cnt[i]+7)&~7;
  s[t] = sum; __syncthreads();
  for (int off = 1; off < 1024; off <<= 1){
    int v = (t >= off) ? s[t-off] : 0;
    __syncthreads();
    s[t] += v;
    __syncthreads();
  }
  int run = (t == 0) ? 0 : s[t-1];
  for (int i = a0; i < a1; ++i){ ptrout[i] = run; run += (cnt[i]+7)&~7; }
  if (t == 1023) ptrout[N] = s[1023];
}

__global__ void fill_kernel(const int* __restrict__ row32, const int* __restrict__ col32,
                            const float* __restrict__ w, const float* __restrict__ dinv,
                            const int* __restrict__ ptrv, int* __restrict__ cnt2,
                            int* __restrict__ srcs, float* __restrict__ vals, int E){
  int e = blockIdx.x*blockDim.x + threadIdx.x;
  if (e >= E) return;
  int r = row32[e], c = col32[e];
  int p = ptrv[c] + atomicAdd(cnt2 + c, 1);
  srcs[p] = r;
  vals[p] = -w[e] * dinv[r] * dinv[c];
}

// Pad slots gather (src=0, val=0): bit-identical arithmetic, L2-hot row.
__global__ void pad_kernel(const int* __restrict__ cnt, const int* __restrict__ ptrv,
                           int* __restrict__ srcs, float* __restrict__ vals, int N){
  int n = blockIdx.x*blockDim.x + threadIdx.x;
  if (n >= N) return;
  int base = ptrv[n];
  int real = cnt[n];
  int padded = ptrv[n+1] - base;
  for (int j = real; j < padded; ++j){ srcs[base+j] = 0; vals[base+j] = 0.f; }
}

// ---------------- SpMM (fp16 gather): y = a*(A xh + diag*x) + b*z ----------
// Gather source is the fp16 shadow (256B/row); epilogue own-row reads fp32 x.
// Optional fp16 shadow output yh for passes whose output is gathered next.
__global__ __launch_bounds__(256) void spmm128_kernel(
    const int* __restrict__ ptrv, const int* __restrict__ srcs, const float* __restrict__ vals,
    const float* __restrict__ dg, const float* __restrict__ x, const half4* __restrict__ xh,
    const float* __restrict__ z,
    float* __restrict__ y, half4* __restrict__ yh, int N, float alpha, float beta){
  int t = threadIdx.x;
  int g = t >> 5, lane = t & 31;
  int node = blockIdx.x*8 + g;
  if (node >= N) return;
  int e0 = ptrv[node], e1 = ptrv[node+1];
  const float4* x4 = (const float4*)x;
  float4 acc = make_float4(0.f,0.f,0.f,0.f);
  for (int eb = e0; eb < e1; eb += 8){
    int j = eb + (lane & 7);
    int s = srcs[j]; float v = vals[j];
    #pragma unroll
    for (int q = 0; q < 8; ++q){
      int   sq = __shfl(s, q, 32);
      float vq = __shfl(v, q, 32);
      half4 hv = xh[(size_t)sq*32 + lane];
      acc.x = fmaf(vq, (float)hv.x, acc.x);
      acc.y = fmaf(vq, (float)hv.y, acc.y);
      acc.z = fmaf(vq, (float)hv.z, acc.z);
      acc.w = fmaf(vq, (float)hv.w, acc.w);
    }
  }
  size_t ii = (size_t)node*32 + lane;
  float dgn = dg[node];
  float4 xi = x4[ii];
  float4 r;
  r.x = alpha*(acc.x + dgn*xi.x);
  r.y = alpha*(acc.y + dgn*xi.y);
  r.z = alpha*(acc.z + dgn*xi.z);
  r.w = alpha*(acc.w + dgn*xi.w);
  if (z){
    float4 zi = ((const float4*)z)[ii];
    r.x = fmaf(beta, zi.x, r.x);
    r.y = fmaf(beta, zi.y, r.y);
    r.z = fmaf(beta, zi.z, r.z);
    r.w = fmaf(beta, zi.w, r.w);
  }
  ((float4*)y)[ii] = r;
  if (yh){
    half4 hr;
    hr.x = (_Float16)r.x; hr.y = (_Float16)r.y;
    hr.z = (_Float16)r.z; hr.w = (_Float16)r.w;
    yh[ii] = hr;
  }
}

// F=32 fp32 gather (L0 x-basis; small traffic) — unchanged from R13.
__global__ __launch_bounds__(256) void spmm32_kernel(
    const int* __restrict__ ptrv, const int* __restrict__ srcs, const float* __restrict__ vals,
    const float* __restrict__ dg, const float* __restrict__ x, const float* __restrict__ z,
    float* __restrict__ y, int N, float alpha, float beta){
  int t = threadIdx.x;
  int g = t >> 3, lane = t & 7;
  int node = blockIdx.x*32 + g;
  if (node >= N) return;
  int e0 = ptrv[node], e1 = ptrv[node+1];
  const float4* x4 = (const float4*)x;
  float4 acc = make_float4(0.f,0.f,0.f,0.f);
  for (int eb = e0; eb < e1; eb += 8){
    int j = eb + lane;
    int s = srcs[j]; float v = vals[j];
    #pragma unroll
    for (int q = 0; q < 8; ++q){
      int   sq = __shfl(s, q, 8);
      float vq = __shfl(v, q, 8);
      float4 xv = x4[(size_t)sq*8 + lane];
      acc.x = fmaf(vq, xv.x, acc.x);
      acc.y = fmaf(vq, xv.y, acc.y);
      acc.z = fmaf(vq, xv.z, acc.z);
      acc.w = fmaf(vq, xv.w, acc.w);
    }
  }
  size_t ii = (size_t)node*8 + lane;
  float dgn = dg[node];
  float4 xi = x4[ii];
  float4 r;
  r.x = alpha*(acc.x + dgn*xi.x);
  r.y = alpha*(acc.y + dgn*xi.y);
  r.z = alpha*(acc.z + dgn*xi.z);
  r.w = alpha*(acc.w + dgn*xi.w);
  if (z){
    float4 zi = ((const float4*)z)[ii];
    r.x = fmaf(beta, zi.x, r.x);
    r.y = fmaf(beta, zi.y, r.y);
    r.z = fmaf(beta, zi.z, r.z);
    r.w = fmaf(beta, zi.w, r.w);
  }
  ((float4*)y)[ii] = r;
}

// ---------------- fused: th2 = 2*(L HRb) - HRb  +  gateB GRU update ---------
// Gathers the fp16 shadow of th1; writes H fp32 + fp16 shadow.
__global__ __launch_bounds__(256) void spmm_gateB_kernel(
    const int* __restrict__ ptrv, const int* __restrict__ srcs, const float* __restrict__ vals,
    const float* __restrict__ dg, const float* __restrict__ th1, const half4* __restrict__ th1h,
    const float* __restrict__ HRb,
    const float* __restrict__ Whh, const float* __restrict__ bhh,
    const float* __restrict__ Zb, const float* __restrict__ gx2b,
    float* __restrict__ H, half4* __restrict__ Hh, int N){
  __shared__ float sp[8][3][128];
  __shared__ float sW[3072];
  int t = threadIdx.x;
  int g = t >> 5, lane = t & 31;
  int node = blockIdx.x*8 + g;
  bool valid = (node < N);
  if (!valid) node = N-1;
  for (int idx = t; idx < 3072; idx += 256) sW[idx] = Whh[idx];
  size_t ii = (size_t)node*32 + lane;
  const float4* x4 = (const float4*)th1;
  const float4* z4 = (const float4*)HRb;
  float4 Zv   = ((const float4*)Zb)[ii];
  float4 Gx   = ((const float4*)gx2b)[ii];
  float4 Hold = ((const float4*)H)[ii];
  float4 zi   = z4[ii];
  int e0 = ptrv[node], e1 = ptrv[node+1];
  float4 acc = make_float4(0.f,0.f,0.f,0.f);
  for (int eb = e0; eb < e1; eb += 8){
    int j = eb + (lane & 7);
    int s = srcs[j]; float v = vals[j];
    #pragma unroll
    for (int q = 0; q < 8; ++q){
      int   sq = __shfl(s, q, 32);
      float vq = __shfl(v, q, 32);
      half4 hv = th1h[(size_t)sq*32 + lane];
      acc.x = fmaf(vq, (float)hv.x, acc.x);
      acc.y = fmaf(vq, (float)hv.y, acc.y);
      acc.z = fmaf(vq, (float)hv.z, acc.z);
      acc.w = fmaf(vq, (float)hv.w, acc.w);
    }
  }
  float dgn = dg[node];
  float4 xi = x4[ii];
  float4 p2;
  p2.x = 2.f*(acc.x + dgn*xi.x) - zi.x;
  p2.y = 2.f*(acc.y + dgn*xi.y) - zi.y;
  p2.z = 2.f*(acc.z + dgn*xi.z) - zi.z;
  p2.w = 2.f*(acc.w + dgn*xi.w) - zi.w;
  ((float4*)&sp[g][0][0])[lane] = zi;
  ((float4*)&sp[g][1][0])[lane] = xi;
  ((float4*)&sp[g][2][0])[lane] = p2;
  __syncthreads();
  int bb8 = lane >> 3;
  const float4* W4 = (const float4*)sW;
  float4 bv = ((const float4*)bhh)[lane & 7];
  float gh0 = bv.x, gh1 = bv.y, gh2 = bv.z, gh3 = bv.w;
  #pragma unroll 1
  for (int k = 0; k < 3; ++k){
    const float* pk = &sp[g][k][bb8*32];
    #pragma unroll
    for (int o = 0; o < 32; o += 4){
      float4 pv = *reinterpret_cast<const float4*>(pk + o);
      #pragma unroll
      for (int oo = 0; oo < 4; ++oo){
        float p = reinterpret_cast<const float*>(&pv)[oo];
        float4 wv = W4[k*256 + (o+oo)*8 + (lane & 7)];
        gh0 = fmaf(p, wv.x, gh0);
        gh1 = fmaf(p, wv.y, gh1);
        gh2 = fmaf(p, wv.z, gh2);
        gh3 = fmaf(p, wv.w, gh3);
      }
    }
  }
  if (valid){
    float4 Hn;
    float Ht;
    Ht = tanhf(Gx.x + gh0); Hn.x = Zv.x*Hold.x + (1.f - Zv.x)*Ht;
    Ht = tanhf(Gx.y + gh1); Hn.y = Zv.y*Hold.y + (1.f - Zv.y)*Ht;
    Ht = tanhf(Gx.z + gh2); Hn.z = Zv.z*Hold.z + (1.f - Zv.z)*Ht;
    Ht = tanhf(Gx.w + gh3); Hn.w = Zv.w*Hold.w + (1.f - Zv.w)*Ht;
    ((float4*)H)[ii] = Hn;
    half4 hh;
    hh.x = (_Float16)Hn.x; hh.y = (_Float16)Hn.y;
    hh.z = (_Float16)Hn.z; hh.w = (_Float16)Hn.w;
    Hh[ii] = hh;
  }
}

// ---------------- transpose layer-0 input ----------------
__global__ void transpose_x_kernel(const float* __restrict__ in, float* __restrict__ out,
                                   int N, int t){
  int idx = blockIdx.x*blockDim.x + threadIdx.x;   // over N*32
  if (idx >= N*32) return;
  int n = idx >> 5; int r = idx & 31; int b = r >> 3; int i = r & 7;
  out[idx] = in[(((size_t)b*12 + t)*N + n)*8 + i];
}

// ---------------- gate A: register-tiled GEMM, acts staged in LDS (R13) ----
// R14: additionally emits HRb's fp16 shadow.
template<int FIN>
__global__ __launch_bounds__(256) void gateA_kernel(
    const float* __restrict__ x0, const float* __restrict__ x1, const float* __restrict__ x2,
    const float* __restrict__ h0, const float* __restrict__ h1, const float* __restrict__ h2,
    const float* __restrict__ Wx, const float* __restrict__ bx,
    const float* __restrict__ Wh, const float* __restrict__ bh,
    float* __restrict__ Zb, float* __restrict__ gx2b,
    float* __restrict__ HRb, _Float16* __restrict__ HRbh, int M){
  __shared__ float sx[3][64*FIN];
  __shared__ float sh[3][64*32];
  int t = threadIdx.x;
  int h = t & 31, ty = t >> 5;
  size_t base = (size_t)blockIdx.x*64;
  int row0 = (int)base + ty*8;

  {
    const float* xm[3] = {x0, x1, x2};
    const float* hm[3] = {h0, h1, h2};
    constexpr int XF4 = FIN/4;
    #pragma unroll
    for (int p = 0; p < 3; ++p){
      float4* dst = (float4*)sx[p];
      const float4* src = (const float4*)xm[p];
      for (int i = t; i < 64*XF4; i += 256){
        int rl = i / XF4, c = i - rl*XF4;
        size_t gr = base + rl; if (gr >= (size_t)M) gr = M-1;
        dst[i] = src[gr*XF4 + c];
      }
      float4* dsth = (float4*)sh[p];
      const float4* srch = (const float4*)hm[p];
      for (int i = t; i < 512; i += 256){
        int rl = i >> 3, c = i & 7;
        size_t gr = base + rl; if (gr >= (size_t)M) gr = M-1;
        dsth[i] = srch[gr*8 + c];
      }
    }
  }
  __syncthreads();
  if (row0 >= M) return;

  float ag0[8]={0,0,0,0,0,0,0,0}, ag1[8]={0,0,0,0,0,0,0,0}, ag2[8]={0,0,0,0,0,0,0,0};
  float az[8]={0,0,0,0,0,0,0,0}, ar[8]={0,0,0,0,0,0,0,0};
  const int gstride = 3*FIN*32;

  #pragma unroll 1
  for (int k3 = 0; k3 < 3; ++k3){
    const float* Ak = sx[k3];
    const float* wb = Wx + k3*FIN*32 + h;
    #pragma unroll 1
    for (int k = 0; k < FIN; k += 4){
      float4 a4[8];
      #pragma unroll
      for (int r = 0; r < 8; ++r)
        a4[r] = *reinterpret_cast<const float4*>(Ak + (ty*8 + r)*FIN + k);
      #pragma unroll
      for (int kk = 0; kk < 4; ++kk){
        float w0 = wb[(k+kk)*32];
        float w1 = wb[(size_t)gstride   + (k+kk)*32];
        float w2 = wb[(size_t)gstride*2 + (k+kk)*32];
        #pragma unroll
        for (int r = 0; r < 8; ++r){
          float av = reinterpret_cast<const float*>(&a4[r])[kk];
          ag0[r] = fmaf(av, w0, ag0[r]);
          ag1[r] = fmaf(av, w1, ag1[r]);
          ag2[r] = fmaf(av, w2, ag2[r]);
        }
      }
    }
  }

  #pragma unroll 1
  for (int k3 = 0; k3 < 3; ++k3){
    const float* Ak = sh[k3];
    const float* wbz = Wh + k3*1024 + h;
    #pragma unroll 1
    for (int k = 0; k < 32; k += 4){
      float4 a4[8];
      #pragma unroll
      for (int r = 0; r < 8; ++r)
        a4[r] = *reinterpret_cast<const float4*>(Ak + (ty*8 + r)*32 + k);
      #pragma unroll
      for (int kk = 0; kk < 4; ++kk){
        float wz = wbz[(k+kk)*32];
        float wr = wbz[3072 + (k+kk)*32];
        #pragma unroll
        for (int r = 0; r < 8; ++r){
          float av = reinterpret_cast<const float*>(&a4[r])[kk];
          az[r] = fmaf(av, wz, az[r]);
          ar[r] = fmaf(av, wr, ar[r]);
        }
      }
    }
  }

  float b0 = bx[h], b1 = bx[32+h], b2 = bx[64+h];
  float bz = bh[h], br = bh[32+h];
  #pragma unroll
  for (int r = 0; r < 8; ++r){
    int rr = row0 + r; if (rr >= M) break;
    float Z = sigmoidf_(ag0[r] + b0 + az[r] + bz);
    float R = sigmoidf_(ag1[r] + b1 + ar[r] + br);
    size_t ix = (size_t)rr*32 + h;
    float hr = sh[0][(ty*8 + r)*32 + h] * R;
    Zb[ix]   = Z;
    gx2b[ix] = ag2[r] + b2;
    HRb[ix]  = hr;
    HRbh[ix] = (_Float16)hr;
  }
}

// ---------------- readout ----------------
__global__ void readout_kernel(const float* __restrict__ H1, const float* __restrict__ muW,
                               const float* __restrict__ mub, const float* __restrict__ sgW,
                               const float* __restrict__ sgb, float* __restrict__ outp, int N){
  int idx = blockIdx.x*blockDim.x + threadIdx.x;   // over 4*N
  if (idx >= 4*N) return;
  int b = idx / N, n = idx - b*N;
  const float* h = H1 + (size_t)n*128 + b*32;
  float m0 = mub[0], m1 = mub[1], s0 = sgb[0], s1 = sgb[1];
  #pragma unroll
  for (int o = 0; o < 32; ++o){
    float v = h[o];
    m0 = fmaf(v, muW[o*2+0], m0);
    m1 = fmaf(v, muW[o*2+1], m1);
    s0 = fmaf(v, sgW[o*2+0], s0);
    s1 = fmaf(v, sgW[o*2+1], s1);
  }
  size_t base = (size_t)(b*N + n)*2;
  outp[base]   = sigmoidf_(m0);
  outp[base+1] = sigmoidf_(m1);
  size_t sb = (size_t)8*N + base;
  outp[sb]   = (s0 > 15.f) ? s0 : log1pf(__expf(s0));
  outp[sb+1] = (s1 > 15.f) ? s1 : log1pf(__expf(s1));
}

__global__ void mean_kernel(const float* __restrict__ H1, float* __restrict__ mixsum, int N){
  int t = threadIdx.x;   // 128 = (b,o)
  int chunk = (N + gridDim.x - 1) / gridDim.x;
  int n0 = blockIdx.x*chunk, n1 = min(N, n0 + chunk);
  float acc = 0.f;
  for (int n = n0; n < n1; ++n) acc += H1[(size_t)n*128 + t];
  atomicAdd(mixsum + t, acc);
}

__global__ void softmax_kernel(const float* __restrict__ mixsum, float* __restrict__ outp,
                               float invN){
  __shared__ float v[128];
  __shared__ float e[128];
  int t = threadIdx.x; int b = t >> 5;
  float m = mixsum[t]*invN;
  v[t] = m; __syncthreads();
  float mx = -1e30f;
  for (int o = 0; o < 32; ++o) mx = fmaxf(mx, v[b*32 + o]);
  float ex = __expf(m - mx);
  e[t] = ex; __syncthreads();
  float s = 0.f;
  for (int o = 0; o < 32; ++o) s += e[b*32 + o];
  outp[t] = ex / s;
}

// ---------------------------------------------------------------------------

extern "C" void kernel_launch(void* const* d_in, const int* in_sizes, int n_in,
                              void* d_out, int out_size, void* d_ws, size_t ws_size,
                              hipStream_t stream){
  const float* in0  = (const float*)d_in[0];
  const void*  eidx = d_in[1];
  const float* ew   = (const float*)d_in[2];
  const float* Wx0  = (const float*)d_in[3];
  const float* Wh0  = (const float*)d_in[4];
  const float* bx0  = (const float*)d_in[5];
  const float* bh0  = (const float*)d_in[6];
  const float* Wx1  = (const float*)d_in[7];
  const float* Wh1  = (const float*)d_in[8];
  const float* bx1  = (const float*)d_in[9];
  const float* bh1  = (const float*)d_in[10];
  const float* muW  = (const float*)d_in[11];
  const float* mub  = (const float*)d_in[12];
  const float* sgW  = (const float*)d_in[13];
  const float* sgb  = (const float*)d_in[14];
  float* outp = (float*)d_out;

  const int N = in_sizes[0] / (4*12*8);
  const int E = in_sizes[1] / 2;
  const int M = 4*N;
  const int EP = E + 8*N;        // padded-edge capacity

  // ---- carve workspace ----
  char* w = (char*)d_ws;
  size_t off = 0;
  auto alloc = [&](size_t bytes)->void*{
    void* p = w + off;
    off += (bytes + 255) & ~(size_t)255;
    return p;
  };
  int*   csr_src = (int*)  alloc((size_t)EP*4);
  float* csr_val = (float*)alloc((size_t)EP*4);
  int*   ptrv    = (int*)  alloc((size_t)(N+1)*4);
  int*   cnt     = (int*)  alloc((size_t)N*4);
  int*   cnt2    = (int*)  alloc((size_t)N*4);
  float* deg     = (float*)alloc((size_t)N*4);
  float* dinv    = (float*)alloc((size_t)N*4);
  float* dgv     = (float*)alloc((size_t)N*4);
  int*   flag    = (int*)  alloc(256);
  float* mixsum  = (float*)alloc(512);
  float* xb0     = (float*)alloc((size_t)N*32*4);
  float* xb1     = (float*)alloc((size_t)N*128*4);  // basis(H0) cache T1
  float* xb2     = (float*)alloc((size_t)N*128*4);  // basis(H0) cache T2
  float* th1     = (float*)alloc((size_t)N*128*4);  // scratch; low 12.8MB doubles as L0 x-basis
  float* th2     = (float*)alloc((size_t)N*128*4);
  float* Zb      = (float*)alloc((size_t)N*128*4);
  float* gx2b    = (float*)alloc((size_t)N*128*4);
  float* HRb     = (float*)alloc((size_t)N*128*4);
  float* H0      = (float*)alloc((size_t)N*128*4);
  float* H1      = (float*)alloc((size_t)N*128*4);
  // fp16 shadows (gathered matrices only)
  half4* s1h  = (half4*)alloc((size_t)N*128*2);   // shared shadow: xb1 / th1
  half4* HRbh = (half4*)alloc((size_t)N*128*2);
  half4* H0h  = (half4*)alloc((size_t)N*128*2);
  half4* H1h  = (half4*)alloc((size_t)N*128*2);
  float* xb1s = th1;                 // [N][32] (L0 x-basis, th1 dead region)
  float* xb2s = th1 + (size_t)N*32;  // [N][32]
  // row32/col32 only live during prep, before th2's first use -> alias into th2
  int* row32 = (int*)th2;
  int* col32 = row32 + E;

  // ---- zero-init (ws is poisoned 0xAA before each call) ----
  (void)hipMemsetAsync(flag,   0, 4, stream);
  (void)hipMemsetAsync(deg,    0, (size_t)N*4, stream);
  (void)hipMemsetAsync(cnt,    0, (size_t)N*4, stream);
  (void)hipMemsetAsync(cnt2,   0, (size_t)N*4, stream);
  (void)hipMemsetAsync(H0,     0, (size_t)N*128*4, stream);
  (void)hipMemsetAsync(H1,     0, (size_t)N*128*4, stream);
  (void)hipMemsetAsync(xb1,    0, (size_t)N*128*4, stream);  // basis(H0=0)=0 at t=0
  (void)hipMemsetAsync(xb2,    0, (size_t)N*128*4, stream);
  (void)hipMemsetAsync(H0h,    0, (size_t)N*128*2, stream);
  (void)hipMemsetAsync(H1h,    0, (size_t)N*128*2, stream);
  (void)hipMemsetAsync(mixsum, 0, 512, stream);

  // ---- preprocessing: dtype detect, degrees, padded CSR build ----
  {
    int ndw = 4096;
    if (ndw > 2*E) ndw = 2*E;
    int nthread = ndw/2 + 1;
    detect_kernel<<<(nthread+255)/256, 256, 0, stream>>>((const unsigned*)eidx, ndw, flag);
  }
  convert_kernel<<<(E+255)/256, 256, 0, stream>>>(eidx, ew, E, flag, row32, col32, deg, cnt);
  node_prep_kernel<<<(N+255)/256, 256, 0, stream>>>(deg, dinv, dgv, N);
  scan_kernel<<<1, 1024, 0, stream>>>(cnt, ptrv, N);
  fill_kernel<<<(E+255)/256, 256, 0, stream>>>(row32, col32, ew, dinv, ptrv, cnt2,
                                               csr_src, csr_val, E);
  pad_kernel<<<(N+255)/256, 256, 0, stream>>>(cnt, ptrv, csr_src, csr_val, N);

  const int g128 = (N+7)/8;    // spmm128 / fused: 8 nodes / 256 threads
  const int g32  = (N+31)/32;  // spmm32: 32 nodes / 256 threads
  const int gG   = (M+63)/64;  // gateA: 64 rows / 256 threads

  for (int t = 0; t < 12; ++t){
    // ===== layer 0 (Fin=8); h-basis from cache (xb1, xb2) =====
    transpose_x_kernel<<<(N*32+255)/256, 256, 0, stream>>>(in0, xb0, N, t);
    spmm32_kernel<<<g32,256,0,stream>>>(ptrv,csr_src,csr_val,dgv, xb0,nullptr,xb1s, N, 1.f, 0.f);
    spmm32_kernel<<<g32,256,0,stream>>>(ptrv,csr_src,csr_val,dgv, xb1s,xb0,  xb2s, N, 2.f,-1.f);
    gateA_kernel<8><<<gG,256,0,stream>>>(xb0,xb1s,xb2s, H0,xb1,xb2,
                                         Wx0,bx0, Wh0,bh0, Zb,gx2b,HRb,(_Float16*)HRbh, M);
    spmm128_kernel<<<g128,256,0,stream>>>(ptrv,csr_src,csr_val,dgv, HRb,HRbh,nullptr,
                                          th1,s1h, N, 1.f, 0.f);
    spmm_gateB_kernel<<<g128,256,0,stream>>>(ptrv,csr_src,csr_val,dgv, th1,s1h,HRb,
                                             Wh0+6144, bh0+64, Zb,gx2b, H0,H0h, N);

    // ===== layer 1 (Fin=32, x = H0); x-basis -> cache (xb1, xb2) =====
    spmm128_kernel<<<g128,256,0,stream>>>(ptrv,csr_src,csr_val,dgv, H0,H0h,nullptr,
                                          xb1,s1h, N, 1.f, 0.f);
    spmm128_kernel<<<g128,256,0,stream>>>(ptrv,csr_src,csr_val,dgv, xb1,s1h,H0,
                                          xb2,nullptr, N, 2.f,-1.f);
    spmm128_kernel<<<g128,256,0,stream>>>(ptrv,csr_src,csr_val,dgv, H1,H1h,nullptr,
                                          th1,s1h, N, 1.f, 0.f);
    spmm128_kernel<<<g128,256,0,stream>>>(ptrv,csr_src,csr_val,dgv, th1,s1h,H1,
                                          th2,nullptr, N, 2.f,-1.f);
    gateA_kernel<32><<<gG,256,0,stream>>>(H0,xb1,xb2, H1,th1,th2,
                                          Wx1,bx1, Wh1,bh1, Zb,gx2b,HRb,(_Float16*)HRbh, M);
    spmm128_kernel<<<g128,256,0,stream>>>(ptrv,csr_src,csr_val,dgv, HRb,HRbh,nullptr,
                                          th1,s1h, N, 1.f, 0.f);
    spmm_gateB_kernel<<<g128,256,0,stream>>>(ptrv,csr_src,csr_val,dgv, th1,s1h,HRb,
                                             Wh1+6144, bh1+64, Zb,gx2b, H1,H1h, N);
  }

  // ---- readout ----
  readout_kernel<<<(4*N+255)/256, 256, 0, stream>>>(H1, muW, mub, sgW, sgb, outp, N);
  mean_kernel<<<256, 128, 0, stream>>>(H1, mixsum, N);
  softmax_kernel<<<1, 128, 0, stream>>>(mixsum, outp + (size_t)16*N, 1.0f/(float)N);
}